// Round 11
// baseline (863.866 us; speedup 1.0000x reference)
//
#include <hip/hip_runtime.h>

typedef float4 f4;

// ---- ws float-offset layout ----
#define F_S0    0        // 64: per-channel W0 scale
#define F_BN0   64       // g[64] be[64] m[64] r[64]
#define F_BN1   320
#define F_BN2   576
#define F_BN3   832      // 256 floats (c<10 valid, rest 0)
#define F_WQ1   1088     // [16][64][4] fp32
#define F_WQ2   5184     // [16][64][4]
#define F_WQ3   9280     // [16][64][4] (zeros for c>=10)
#define F_WI0   13376    // int8 W0 tiled [768][64][4] = 196608 B
#define F_WQ0   62528    // fp32 W0 tiled [768][64][4] = 196608 floats
#define WS_NEED_F32 ((size_t)(F_WQ0 + 196608) * 4)

struct InPtrs { const float* p[25]; };

// ---------------- prep: fp32 scales/weights/BN consts (np-f32 exact ops) ----------------
__global__ __launch_bounds__(256) void qtfc_prep(InPtrs P, float* __restrict__ wsf, int wf32) {
#pragma clang fp contract(off)
  __shared__ float red[256];
  const int tid = threadIdx.x, b = blockIdx.x;
  if (b < 64) {
    const int c = b;                       // output channel
    const float* W = P.p[1];
    float mx = 0.f;
    for (int k = tid; k < 3072; k += 256) mx = fmaxf(mx, fabsf(W[c * 3072 + k]));
    red[tid] = mx; __syncthreads();
    for (int s = 128; s > 0; s >>= 1) { if (tid < s) red[tid] = fmaxf(red[tid], red[tid + s]); __syncthreads(); }
    const float sv = fmaxf(__fdiv_rn(red[0], 7.f), 1e-8f);
    signed char* wi = (signed char*)(wsf + F_WI0);
    for (int k = tid; k < 3072; k += 256) {
      const float r = rintf(__fdiv_rn(W[c * 3072 + k], sv));
      const int idx = (k >> 2) * 256 + c * 4 + (k & 3);   // [chunk][ch][4]
      wi[idx] = (signed char)(int)r;
      if (wf32) wsf[F_WQ0 + idx] = __fmul_rn(r, sv);
    }
    if (tid == 0) {
      wsf[F_S0 + c] = sv;
      const float gg = P.p[3][c], be = P.p[4][c], m = P.p[5][c], v = P.p[6][c];
      const float rr = __fdiv_rn(1.f, __fsqrt_rn(__fadd_rn(v, 1e-5f)));
      wsf[F_BN0 + c] = gg; wsf[F_BN0 + 64 + c] = be; wsf[F_BN0 + 128 + c] = m; wsf[F_BN0 + 192 + c] = rr;
    }
  } else if (b < 192) {
    const int lay = b >> 6, c = b & 63;    // lay = 1,2
    const float* W = P.p[1 + 6 * lay];
    red[tid] = (tid < 64) ? fabsf(W[c * 64 + tid]) : 0.f; __syncthreads();
    for (int s = 128; s > 0; s >>= 1) { if (tid < s) red[tid] = fmaxf(red[tid], red[tid + s]); __syncthreads(); }
    const float sv = fmaxf(__fdiv_rn(red[0], 7.f), 1e-8f);
    float* wq = wsf + (lay == 1 ? F_WQ1 : F_WQ2);
    if (tid < 64) {
      const int k = tid;
      wq[(k >> 2) * 256 + c * 4 + (k & 3)] = __fmul_rn(rintf(__fdiv_rn(W[c * 64 + k], sv)), sv);
    }
    if (tid == 0) {
      const int base = (lay == 1) ? F_BN1 : F_BN2;
      const float gg = P.p[3 + 6 * lay][c], be = P.p[4 + 6 * lay][c];
      const float m = P.p[5 + 6 * lay][c], v = P.p[6 + 6 * lay][c];
      const float rr = __fdiv_rn(1.f, __fsqrt_rn(__fadd_rn(v, 1e-5f)));
      wsf[base + c] = gg; wsf[base + 64 + c] = be; wsf[base + 128 + c] = m; wsf[base + 192 + c] = rr;
    }
  } else {
    // W3: zero-pad then per-tensor quant over 10x64
    for (int i = tid; i < 4096; i += 256) wsf[F_WQ3 + i] = 0.f;
    for (int i = tid; i < 256; i += 256) wsf[F_BN3 + i] = 0.f;
    __syncthreads();
    const float* W = P.p[19];
    float mx = 0.f;
    for (int k = tid; k < 640; k += 256) mx = fmaxf(mx, fabsf(W[k]));
    red[tid] = mx; __syncthreads();
    for (int s = 128; s > 0; s >>= 1) { if (tid < s) red[tid] = fmaxf(red[tid], red[tid + s]); __syncthreads(); }
    const float sv = fmaxf(__fdiv_rn(red[0], 7.f), 1e-8f);
    for (int i = tid; i < 640; i += 256) {
      const int c = i >> 6, k = i & 63;
      wsf[F_WQ3 + (k >> 2) * 256 + c * 4 + (k & 3)] = __fmul_rn(rintf(__fdiv_rn(W[i], sv)), sv);
    }
    if (tid < 10) {
      const float gg = P.p[21][tid], be = P.p[22][tid], m = P.p[23][tid], v = P.p[24][tid];
      const float rr = __fdiv_rn(1.f, __fsqrt_rn(__fadd_rn(v, 1e-5f)));
      wsf[F_BN3 + tid] = gg; wsf[F_BN3 + 16 + tid] = be; wsf[F_BN3 + 32 + tid] = m; wsf[F_BN3 + 48 + tid] = rr;
    }
  }
}

// ---------------- exact-np helpers ----------------
__device__ __forceinline__ float bn_act4(float hv, float g, float be, float m, float r) {
#pragma clang fp contract(off)
  const float bnv = __fadd_rn(__fmul_rn(__fmul_rn(g, __fsub_rn(hv, m)), r), be);
  const float y = fminf(fmaxf(bnv, -1.f), 1.f);
  return __fdiv_rn(rintf(__fmul_rn(y, 7.f)), 7.f);
}
__device__ __forceinline__ float lutq(float v, const float* lut) {
#pragma clang fp contract(off)
  const float y = fminf(fmaxf(v, -1.f), 1.f);
  const float r = rintf(__fmul_rn(y, 127.f));
  return lut[(int)r + 127];   // == __fdiv_rn(r, 127.f)
}
__device__ __forceinline__ f4 q4(f4 v, const float* lut) {
  f4 q; q.x = lutq(v.x, lut); q.y = lutq(v.y, lut); q.z = lutq(v.z, lut); q.w = lutq(v.w, lut);
  return q;
}
__device__ __forceinline__ f4 dec8(int d, float sv) {
#pragma clang fp contract(off)
  f4 w;
  w.x = __fmul_rn((float)((signed char)(d & 255)), sv);
  w.y = __fmul_rn((float)((signed char)((d >> 8) & 255)), sv);
  w.z = __fmul_rn((float)((signed char)((d >> 16) & 255)), sv);
  w.w = __fmul_rn((float)((signed char)((d >> 24) & 255)), sv);
  return w;
}

// ---- main: 16 rows/wave; lane = (rg = l>>4 row-group, cg = l&15 ch-group) ----
// lane owns rows rg*4..rg*4+3, channels {cg, cg+16, cg+32, cg+48}: acc[4][4]
template<int W8>
__global__ __launch_bounds__(256) void qtfc_main(const float* __restrict__ x,
                                                 const float* __restrict__ wsf,
                                                 float* __restrict__ out) {
#pragma clang fp contract(off)
  // 4 wave regions x 2176 floats (x-dbuf 2x16x17 f4; later a1 [0:1024), a2 [1024:2048)) + lut
  __shared__ __align__(16) float smem[8960];
  const int tid = threadIdx.x, w = tid >> 6, l = tid & 63;
  float* R = smem + w * 2176;
  f4* xt = (f4*)R;
  float* lut = smem + 8704;
  const int row0w = blockIdx.x * 64 + w * 16;

  if (tid < 255) lut[tid] = __fdiv_rn((float)(tid - 127), 127.f);

  const int cg = l & 15, rg = l >> 4;
  const int sr = l >> 2, s0 = l & 3;           // staging: row sr, slots s0+4j
  const float* xb0 = x + (long)(row0w + sr) * 3072 + s0 * 4;
  f4* xs0 = xt + sr * 17 + s0;                 // writes [0],[4],[8],[12]
  f4* xs1 = xs0 + 272;
  const f4* xr0 = xt + rg * 68;                // reads [r4*17+cc]
  const f4* xr1 = xr0 + 272;

  const f4* wq0 = (const f4*)(wsf + F_WQ0);
  const int* wi0 = (const int*)(wsf + F_WI0);
  float sv[4];
  if (W8) {
#pragma unroll
    for (int j = 0; j < 4; ++j) sv[j] = wsf[F_S0 + cg + 16 * j];
  }

  float acc[4][4], hs[4][4];
#pragma unroll
  for (int r = 0; r < 4; ++r)
#pragma unroll
    for (int j = 0; j < 4; ++j) { acc[r][j] = 0.f; hs[r][j] = 0.f; }

  __syncthreads();                             // lut visible

  // prologue: stage tile 0, prefetch tile 1
  f4 g0 = *(const f4*)(xb0);
  f4 g1 = *(const f4*)(xb0 + 16);
  f4 g2 = *(const f4*)(xb0 + 32);
  f4 g3 = *(const f4*)(xb0 + 48);
  xs0[0] = q4(g0, lut); xs0[4] = q4(g1, lut);
  xs0[8] = q4(g2, lut); xs0[12] = q4(g3, lut);
  g0 = *(const f4*)(xb0 + 64);  g1 = *(const f4*)(xb0 + 80);
  g2 = *(const f4*)(xb0 + 96);  g3 = *(const f4*)(xb0 + 112);

  f4 wA[4], wB[4];
  int dA[4], dB[4];

#define LDW(W_, D_, T_, CC_)                                       \
  { if (!W8) {                                                     \
      const f4* _wb = wq0 + (long)(T_) * 1024 + cg;                \
      _Pragma("unroll")                                            \
      for (int j = 0; j < 4; ++j) W_[j] = _wb[(CC_) * 64 + 16 * j];\
    } else {                                                       \
      const int* _ib = wi0 + (long)(T_) * 1024 + cg;               \
      _Pragma("unroll")                                            \
      for (int j = 0; j < 4; ++j) D_[j] = _ib[(CC_) * 64 + 16 * j];\
    } }

#define FMAG(W_, D_, CC_, XR_)                                     \
  { f4 _wf[4];                                                     \
    _Pragma("unroll")                                              \
    for (int j = 0; j < 4; ++j) _wf[j] = W8 ? dec8(D_[j], sv[j]) : W_[j]; \
    _Pragma("unroll")                                              \
    for (int r4 = 0; r4 < 4; ++r4) {                               \
      const f4 xv = (XR_)[r4 * 17 + (CC_)];                        \
      _Pragma("unroll")                                            \
      for (int j = 0; j < 4; ++j) {                                \
        float a = acc[r4][j];                                      \
        a = __fmaf_rn(xv.x, _wf[j].x, a);                          \
        a = __fmaf_rn(xv.y, _wf[j].y, a);                          \
        a = __fmaf_rn(xv.z, _wf[j].z, a);                          \
        a = __fmaf_rn(xv.w, _wf[j].w, a);                          \
        acc[r4][j] = a;                                            \
      } } }

  LDW(wA, dA, 0, 0);

#pragma unroll 1
  for (int t = 0; t < 48; ++t) {
    const f4* xr = (t & 1) ? xr1 : xr0;
    f4* xsn = (t & 1) ? xs0 : xs1;
    const int tn = (t + 2 < 48) ? t + 2 : 47;

    LDW(wB, dB, t, 1);  FMAG(wA, dA, 0, xr);
    LDW(wA, dA, t, 2);  FMAG(wB, dB, 1, xr);
    LDW(wB, dB, t, 3);
    if (t < 47) { xsn[0] = q4(g0, lut); xsn[4] = q4(g1, lut); }
    FMAG(wA, dA, 2, xr);
    LDW(wA, dA, t, 4);
    if (t < 47) { xsn[8] = q4(g2, lut); xsn[12] = q4(g3, lut); }
    FMAG(wB, dB, 3, xr);
    LDW(wB, dB, t, 5);  FMAG(wA, dA, 4, xr);
    LDW(wA, dA, t, 6);  FMAG(wB, dB, 5, xr);
    LDW(wB, dB, t, 7);  FMAG(wA, dA, 6, xr);
    LDW(wA, dA, t, 8);  FMAG(wB, dB, 7, xr);
    LDW(wB, dB, t, 9);
    g0 = *(const f4*)(xb0 + tn * 64);
    g1 = *(const f4*)(xb0 + tn * 64 + 16);
    FMAG(wA, dA, 8, xr);
    LDW(wA, dA, t, 10);
    g2 = *(const f4*)(xb0 + tn * 64 + 32);
    g3 = *(const f4*)(xb0 + tn * 64 + 48);
    FMAG(wB, dB, 9, xr);
    LDW(wB, dB, t, 11); FMAG(wA, dA, 10, xr);
    LDW(wA, dA, t, 12); FMAG(wB, dB, 11, xr);
    LDW(wB, dB, t, 13); FMAG(wA, dA, 12, xr);
    LDW(wA, dA, t, 14); FMAG(wB, dB, 13, xr);
    LDW(wB, dB, t, 15); FMAG(wA, dA, 14, xr);
    if (t < 47) { LDW(wA, dA, t + 1, 0); } else { LDW(wA, dA, t, 15); }
    FMAG(wB, dB, 15, xr);

    if ((t % 6) == 5) {   // KC=384 boundary: sequential fp32 block-sum combine
#pragma unroll
      for (int r = 0; r < 4; ++r)
#pragma unroll
        for (int j = 0; j < 4; ++j) { hs[r][j] = __fadd_rn(hs[r][j], acc[r][j]); acc[r][j] = 0.f; }
    }
  }
#undef LDW
#undef FMAG

  float* xa1 = R;            // a1 [16][64]
  float* a2  = R + 1024;

  // ---- layer-0 epilogue: BN + 4-bit act -> a1 ----
  {
#pragma unroll
    for (int j = 0; j < 4; ++j) {
      const int ch = cg + 16 * j;
      const float g = wsf[F_BN0 + ch], be = wsf[F_BN0 + 64 + ch];
      const float m = wsf[F_BN0 + 128 + ch], rr = wsf[F_BN0 + 192 + ch];
#pragma unroll
      for (int r4 = 0; r4 < 4; ++r4)
        xa1[(rg * 4 + r4) * 64 + ch] = bn_act4(hs[r4][j], g, be, m, rr);
    }
  }

  // ---- layer 1: a1 -> a2 (lane = channel l, 16 rows) ----
  {
    const f4* wq1 = (const f4*)(wsf + F_WQ1);
    const f4* a14 = (const f4*)xa1;
    float a1c[16];
#pragma unroll
    for (int r = 0; r < 16; ++r) a1c[r] = 0.f;
#pragma unroll
    for (int cc = 0; cc < 16; ++cc) {
      const f4 wf = wq1[cc * 64 + l];
#pragma unroll
      for (int r = 0; r < 16; ++r) {
        const f4 xv = a14[r * 16 + cc];
        float a = a1c[r];
        a = __fmaf_rn(xv.x, wf.x, a);
        a = __fmaf_rn(xv.y, wf.y, a);
        a = __fmaf_rn(xv.z, wf.z, a);
        a = __fmaf_rn(xv.w, wf.w, a);
        a1c[r] = a;
      }
    }
    const float g = wsf[F_BN1 + l], be = wsf[F_BN1 + 64 + l];
    const float m = wsf[F_BN1 + 128 + l], rr = wsf[F_BN1 + 192 + l];
#pragma unroll
    for (int r = 0; r < 16; ++r)
      a2[r * 64 + l] = bn_act4(a1c[r], g, be, m, rr);
  }

  // ---- layer 2: a2 -> a1 ----
  {
    const f4* wq2 = (const f4*)(wsf + F_WQ2);
    const f4* a24 = (const f4*)a2;
    float a2c[16];
#pragma unroll
    for (int r = 0; r < 16; ++r) a2c[r] = 0.f;
#pragma unroll
    for (int cc = 0; cc < 16; ++cc) {
      const f4 wf = wq2[cc * 64 + l];
#pragma unroll
      for (int r = 0; r < 16; ++r) {
        const f4 xv = a24[r * 16 + cc];
        float a = a2c[r];
        a = __fmaf_rn(xv.x, wf.x, a);
        a = __fmaf_rn(xv.y, wf.y, a);
        a = __fmaf_rn(xv.z, wf.z, a);
        a = __fmaf_rn(xv.w, wf.w, a);
        a2c[r] = a;
      }
    }
    const float g = wsf[F_BN2 + l], be = wsf[F_BN2 + 64 + l];
    const float m = wsf[F_BN2 + 128 + l], rr = wsf[F_BN2 + 192 + l];
#pragma unroll
    for (int r = 0; r < 16; ++r)
      xa1[r * 64 + l] = bn_act4(a2c[r], g, be, m, rr);
  }

  // ---- layer 3: 10 outputs, BN affine, no act ----
  {
    const f4* wq3 = (const f4*)(wsf + F_WQ3);
    const f4* a14 = (const f4*)xa1;
    float a3c[16];
#pragma unroll
    for (int r = 0; r < 16; ++r) a3c[r] = 0.f;
#pragma unroll
    for (int cc = 0; cc < 16; ++cc) {
      const f4 wf = wq3[cc * 64 + l];
#pragma unroll
      for (int r = 0; r < 16; ++r) {
        const f4 xv = a14[r * 16 + cc];
        float a = a3c[r];
        a = __fmaf_rn(xv.x, wf.x, a);
        a = __fmaf_rn(xv.y, wf.y, a);
        a = __fmaf_rn(xv.z, wf.z, a);
        a = __fmaf_rn(xv.w, wf.w, a);
        a3c[r] = a;
      }
    }
    if (l < 10) {
      const float g = wsf[F_BN3 + l], be = wsf[F_BN3 + 16 + l];
      const float m = wsf[F_BN3 + 32 + l], rr = wsf[F_BN3 + 48 + l];
#pragma unroll
      for (int r = 0; r < 16; ++r) {
        const float o = __fadd_rn(__fmul_rn(__fmul_rn(g, __fsub_rn(a3c[r], m)), rr), be);
        out[(long)(row0w + r) * 10 + l] = o;
      }
    }
  }
}

extern "C" void kernel_launch(void* const* d_in, const int* in_sizes, int n_in,
                              void* d_out, int out_size, void* d_ws, size_t ws_size,
                              hipStream_t stream) {
  (void)in_sizes; (void)n_in; (void)out_size;
  InPtrs P;
  for (int i = 0; i < 25; ++i) P.p[i] = (const float*)d_in[i];
  float* wsf = (float*)d_ws;
  const int wf32 = (ws_size >= WS_NEED_F32) ? 1 : 0;
  qtfc_prep<<<193, 256, 0, stream>>>(P, wsf, wf32);
  if (wf32)
    qtfc_main<0><<<512, 256, 0, stream>>>((const float*)d_in[0], wsf, (float*)d_out);
  else
    qtfc_main<1><<<512, 256, 0, stream>>>((const float*)d_in[0], wsf, (float*)d_out);
}

// Round 12
// 532.055 us; speedup vs baseline: 1.6236x; 1.6236x over previous
//
#include <hip/hip_runtime.h>

typedef float4 f4;

// ---- ws float-offset layout ----
#define F_S0    0        // 64: per-channel W0 scale
#define F_BN0   64       // g[64] be[64] m[64] r[64]
#define F_BN1   320
#define F_BN2   576
#define F_BN3   832      // 256 floats (c<10 valid, rest 0)
#define F_WQ1   1088     // [16][64][4] fp32
#define F_WQ2   5184     // [16][64][4]
#define F_WQ3   9280     // [16][64][4] (zeros for c>=10)
#define F_WI0   13376    // int8 W0 tiled [768][64][4] = 196608 B
#define F_WQ0   62528    // fp32 W0 tiled [768][64][4] = 196608 floats
#define WS_NEED_F32 ((size_t)(F_WQ0 + 196608) * 4)

struct InPtrs { const float* p[25]; };

// ---------------- prep: fp32 scales/weights/BN consts (np-f32 exact ops) ----------------
__global__ __launch_bounds__(256) void qtfc_prep(InPtrs P, float* __restrict__ wsf, int wf32) {
#pragma clang fp contract(off)
  __shared__ float red[256];
  const int tid = threadIdx.x, b = blockIdx.x;
  if (b < 64) {
    const int c = b;                       // output channel
    const float* W = P.p[1];
    float mx = 0.f;
    for (int k = tid; k < 3072; k += 256) mx = fmaxf(mx, fabsf(W[c * 3072 + k]));
    red[tid] = mx; __syncthreads();
    for (int s = 128; s > 0; s >>= 1) { if (tid < s) red[tid] = fmaxf(red[tid], red[tid + s]); __syncthreads(); }
    const float sv = fmaxf(__fdiv_rn(red[0], 7.f), 1e-8f);
    signed char* wi = (signed char*)(wsf + F_WI0);
    for (int k = tid; k < 3072; k += 256) {
      const float r = rintf(__fdiv_rn(W[c * 3072 + k], sv));
      const int idx = (k >> 2) * 256 + c * 4 + (k & 3);   // [chunk][ch][4]
      wi[idx] = (signed char)(int)r;
      if (wf32) wsf[F_WQ0 + idx] = __fmul_rn(r, sv);
    }
    if (tid == 0) {
      wsf[F_S0 + c] = sv;
      const float gg = P.p[3][c], be = P.p[4][c], m = P.p[5][c], v = P.p[6][c];
      const float rr = __fdiv_rn(1.f, __fsqrt_rn(__fadd_rn(v, 1e-5f)));
      wsf[F_BN0 + c] = gg; wsf[F_BN0 + 64 + c] = be; wsf[F_BN0 + 128 + c] = m; wsf[F_BN0 + 192 + c] = rr;
    }
  } else if (b < 192) {
    const int lay = b >> 6, c = b & 63;    // lay = 1,2
    const float* W = P.p[1 + 6 * lay];
    red[tid] = (tid < 64) ? fabsf(W[c * 64 + tid]) : 0.f; __syncthreads();
    for (int s = 128; s > 0; s >>= 1) { if (tid < s) red[tid] = fmaxf(red[tid], red[tid + s]); __syncthreads(); }
    const float sv = fmaxf(__fdiv_rn(red[0], 7.f), 1e-8f);
    float* wq = wsf + (lay == 1 ? F_WQ1 : F_WQ2);
    if (tid < 64) {
      const int k = tid;
      wq[(k >> 2) * 256 + c * 4 + (k & 3)] = __fmul_rn(rintf(__fdiv_rn(W[c * 64 + k], sv)), sv);
    }
    if (tid == 0) {
      const int base = (lay == 1) ? F_BN1 : F_BN2;
      const float gg = P.p[3 + 6 * lay][c], be = P.p[4 + 6 * lay][c];
      const float m = P.p[5 + 6 * lay][c], v = P.p[6 + 6 * lay][c];
      const float rr = __fdiv_rn(1.f, __fsqrt_rn(__fadd_rn(v, 1e-5f)));
      wsf[base + c] = gg; wsf[base + 64 + c] = be; wsf[base + 128 + c] = m; wsf[base + 192 + c] = rr;
    }
  } else {
    // W3: zero-pad then per-tensor quant over 10x64
    for (int i = tid; i < 4096; i += 256) wsf[F_WQ3 + i] = 0.f;
    for (int i = tid; i < 256; i += 256) wsf[F_BN3 + i] = 0.f;
    __syncthreads();
    const float* W = P.p[19];
    float mx = 0.f;
    for (int k = tid; k < 640; k += 256) mx = fmaxf(mx, fabsf(W[k]));
    red[tid] = mx; __syncthreads();
    for (int s = 128; s > 0; s >>= 1) { if (tid < s) red[tid] = fmaxf(red[tid], red[tid + s]); __syncthreads(); }
    const float sv = fmaxf(__fdiv_rn(red[0], 7.f), 1e-8f);
    for (int i = tid; i < 640; i += 256) {
      const int c = i >> 6, k = i & 63;
      wsf[F_WQ3 + (k >> 2) * 256 + c * 4 + (k & 3)] = __fmul_rn(rintf(__fdiv_rn(W[i], sv)), sv);
    }
    if (tid < 10) {
      const float gg = P.p[21][tid], be = P.p[22][tid], m = P.p[23][tid], v = P.p[24][tid];
      const float rr = __fdiv_rn(1.f, __fsqrt_rn(__fadd_rn(v, 1e-5f)));
      wsf[F_BN3 + tid] = gg; wsf[F_BN3 + 16 + tid] = be; wsf[F_BN3 + 32 + tid] = m; wsf[F_BN3 + 48 + tid] = rr;
    }
  }
}

// ---------------- exact-np helpers ----------------
__device__ __forceinline__ float bn_act4(float hv, float g, float be, float m, float r) {
#pragma clang fp contract(off)
  const float bnv = __fadd_rn(__fmul_rn(__fmul_rn(g, __fsub_rn(hv, m)), r), be);
  const float y = fminf(fmaxf(bnv, -1.f), 1.f);
  return __fdiv_rn(rintf(__fmul_rn(y, 7.f)), 7.f);
}
__device__ __forceinline__ float lutq(float v, const float* lut) {
#pragma clang fp contract(off)
  const float y = fminf(fmaxf(v, -1.f), 1.f);
  const float r = rintf(__fmul_rn(y, 127.f));
  return lut[(int)r + 127];   // == __fdiv_rn(r, 127.f)
}
__device__ __forceinline__ f4 q4(f4 v, const float* lut) {
  f4 q; q.x = lutq(v.x, lut); q.y = lutq(v.y, lut); q.z = lutq(v.z, lut); q.w = lutq(v.w, lut);
  return q;
}
__device__ __forceinline__ f4 dec8(int d, float sv) {
#pragma clang fp contract(off)
  f4 w;
  w.x = __fmul_rn((float)((signed char)(d & 255)), sv);
  w.y = __fmul_rn((float)((signed char)((d >> 8) & 255)), sv);
  w.z = __fmul_rn((float)((signed char)((d >> 16) & 255)), sv);
  w.w = __fmul_rn((float)((signed char)((d >> 24) & 255)), sv);
  return w;
}

// ---- main: 8 rows/wave; lane = (rg=l>>4 -> rows rg*2..rg*2+1, cg=l&15 -> ch {cg,+16,+32,+48}) ----
template<int W8>
__global__ __launch_bounds__(256) void qtfc_main(const float* __restrict__ x,
                                                 const float* __restrict__ wsf,
                                                 float* __restrict__ out) {
#pragma clang fp contract(off)
  // per wave region: 1120 floats (x dbuf 2 x [4 rg][35 f4]); lut at end
  __shared__ __align__(16) float smem[4 * 1120 + 256];
  const int tid = threadIdx.x, w = tid >> 6, l = tid & 63;
  float* R = smem + w * 1120;
  float* lut = smem + 4480;
  const int row0w = blockIdx.x * 32 + w * 8;

  if (tid < 255) lut[tid] = __fdiv_rn((float)(tid - 127), 127.f);

  const int cg = l & 15, rg = l >> 4;
  const int sr = l >> 3, s0 = l & 7;
  const float* xb = x + (long)(row0w + sr) * 3072 + s0 * 4;

  f4* xsA = (f4*)R + (sr >> 1) * 35 + (sr & 1) * 17 + s0;   // writes at [0] and [8]
  f4* xsB = xsA + 140;
  const f4* xrA = (const f4*)R + rg * 35;                   // reads [r2*17 + cc]
  const f4* xrB = xrA + 140;

  const f4* wp2 = (const f4*)(wsf + F_WQ0) + cg;            // rolling base (bump 256 f4 per 4 cc)
  const int* ip2 = (const int*)(wsf + F_WI0) + cg;
  float sv[4];
  if (W8) {
#pragma unroll
    for (int j = 0; j < 4; ++j) sv[j] = wsf[F_S0 + cg + 16 * j];
  }

  float acc[2][4], hs[2][4];
#pragma unroll
  for (int r = 0; r < 2; ++r)
#pragma unroll
    for (int j = 0; j < 4; ++j) { acc[r][j] = 0.f; hs[r][j] = 0.f; }

  __syncthreads();                                          // lut visible

  // prologue: stage tile 0, prefetch tile 1
  f4 g0 = *(const f4*)(xb);
  f4 g1 = *(const f4*)(xb + 32);
  xsA[0] = q4(g0, lut);
  xsA[8] = q4(g1, lut);
  g0 = *(const f4*)(xb + 64);
  g1 = *(const f4*)(xb + 96);

  f4 wa0, wa1, wa2, wa3, wb0, wb1, wb2, wb3;
  int da0 = 0, da1 = 0, da2 = 0, da3 = 0, db0 = 0, db1 = 0, db2 = 0, db3 = 0;

#define LDW(W0_, W1_, W2_, W3_, D0_, D1_, D2_, D3_, CC_)           \
  { const int _o = ((CC_) & 3) * 64;                               \
    if (!W8) { W0_ = wp2[_o]; W1_ = wp2[_o + 16];                  \
               W2_ = wp2[_o + 32]; W3_ = wp2[_o + 48]; }           \
    else     { D0_ = ip2[_o]; D1_ = ip2[_o + 16];                  \
               D2_ = ip2[_o + 32]; D3_ = ip2[_o + 48]; } }

#define BUMP() { if (!W8) wp2 += 256; else ip2 += 256; }

#define FMAC(W0_, W1_, W2_, W3_, D0_, D1_, D2_, D3_, CC_, XR_)     \
  { f4 _w0, _w1, _w2, _w3;                                         \
    if (!W8) { _w0 = W0_; _w1 = W1_; _w2 = W2_; _w3 = W3_; }       \
    else { _w0 = dec8(D0_, sv[0]); _w1 = dec8(D1_, sv[1]);         \
           _w2 = dec8(D2_, sv[2]); _w3 = dec8(D3_, sv[3]); }       \
    const f4 _x0 = (XR_)[(CC_)];                                   \
    const f4 _x1 = (XR_)[17 + (CC_)];                              \
    _Pragma("unroll")                                              \
    for (int _j = 0; _j < 4; ++_j) {                               \
      const f4 _wf = (_j == 0) ? _w0 : (_j == 1) ? _w1 : (_j == 2) ? _w2 : _w3; \
      float _a0 = acc[0][_j], _a1 = acc[1][_j];                    \
      _a0 = __fmaf_rn(_x0.x, _wf.x, _a0); _a1 = __fmaf_rn(_x1.x, _wf.x, _a1); \
      _a0 = __fmaf_rn(_x0.y, _wf.y, _a0); _a1 = __fmaf_rn(_x1.y, _wf.y, _a1); \
      _a0 = __fmaf_rn(_x0.z, _wf.z, _a0); _a1 = __fmaf_rn(_x1.z, _wf.z, _a1); \
      _a0 = __fmaf_rn(_x0.w, _wf.w, _a0); _a1 = __fmaf_rn(_x1.w, _wf.w, _a1); \
      acc[0][_j] = _a0; acc[1][_j] = _a1;                          \
    } }

  LDW(wa0, wa1, wa2, wa3, da0, da1, da2, da3, 0);   // tile 0, cc 0

#pragma unroll 1
  for (int t = 0; t < 48; ++t) {
    const f4* xr = (t & 1) ? xrB : xrA;
    f4* xsn = (t & 1) ? xsA : xsB;
    const int tn = (t + 2 < 48) ? t + 2 : 47;

    LDW(wb0, wb1, wb2, wb3, db0, db1, db2, db3, 1);  FMAC(wa0, wa1, wa2, wa3, da0, da1, da2, da3, 0, xr);
    LDW(wa0, wa1, wa2, wa3, da0, da1, da2, da3, 2);  FMAC(wb0, wb1, wb2, wb3, db0, db1, db2, db3, 1, xr);
    LDW(wb0, wb1, wb2, wb3, db0, db1, db2, db3, 3);
    if (t < 47) xsn[0] = q4(g0, lut);
    FMAC(wa0, wa1, wa2, wa3, da0, da1, da2, da3, 2, xr);
    BUMP();
    LDW(wa0, wa1, wa2, wa3, da0, da1, da2, da3, 4);
    if (t < 47) xsn[8] = q4(g1, lut);
    FMAC(wb0, wb1, wb2, wb3, db0, db1, db2, db3, 3, xr);
    LDW(wb0, wb1, wb2, wb3, db0, db1, db2, db3, 5);  FMAC(wa0, wa1, wa2, wa3, da0, da1, da2, da3, 4, xr);
    LDW(wa0, wa1, wa2, wa3, da0, da1, da2, da3, 6);  FMAC(wb0, wb1, wb2, wb3, db0, db1, db2, db3, 5, xr);
    LDW(wb0, wb1, wb2, wb3, db0, db1, db2, db3, 7);  FMAC(wa0, wa1, wa2, wa3, da0, da1, da2, da3, 6, xr);
    BUMP();
    LDW(wa0, wa1, wa2, wa3, da0, da1, da2, da3, 8);  FMAC(wb0, wb1, wb2, wb3, db0, db1, db2, db3, 7, xr);
    LDW(wb0, wb1, wb2, wb3, db0, db1, db2, db3, 9);
    g0 = *(const f4*)(xb + tn * 64);
    FMAC(wa0, wa1, wa2, wa3, da0, da1, da2, da3, 8, xr);
    LDW(wa0, wa1, wa2, wa3, da0, da1, da2, da3, 10);
    g1 = *(const f4*)(xb + tn * 64 + 32);
    FMAC(wb0, wb1, wb2, wb3, db0, db1, db2, db3, 9, xr);
    LDW(wb0, wb1, wb2, wb3, db0, db1, db2, db3, 11); FMAC(wa0, wa1, wa2, wa3, da0, da1, da2, da3, 10, xr);
    BUMP();
    LDW(wa0, wa1, wa2, wa3, da0, da1, da2, da3, 12); FMAC(wb0, wb1, wb2, wb3, db0, db1, db2, db3, 11, xr);
    LDW(wb0, wb1, wb2, wb3, db0, db1, db2, db3, 13); FMAC(wa0, wa1, wa2, wa3, da0, da1, da2, da3, 12, xr);
    LDW(wa0, wa1, wa2, wa3, da0, da1, da2, da3, 14); FMAC(wb0, wb1, wb2, wb3, db0, db1, db2, db3, 13, xr);
    LDW(wb0, wb1, wb2, wb3, db0, db1, db2, db3, 15); FMAC(wa0, wa1, wa2, wa3, da0, da1, da2, da3, 14, xr);
    if (t < 47) {
      BUMP();
      LDW(wa0, wa1, wa2, wa3, da0, da1, da2, da3, 0);  // next tile cc 0
    }
    FMAC(wb0, wb1, wb2, wb3, db0, db1, db2, db3, 15, xr);

    if ((t % 6) == 5) {   // KC=384 boundary: sequential fp32 block-sum combine
#pragma unroll
      for (int r = 0; r < 2; ++r)
#pragma unroll
        for (int j = 0; j < 4; ++j) { hs[r][j] = __fadd_rn(hs[r][j], acc[r][j]); acc[r][j] = 0.f; }
    }
  }
#undef LDW
#undef BUMP
#undef FMAC

  float* xa1 = R;            // a1 [8][64]
  float* a2  = R + 512;

  // ---- layer-0 epilogue: BN + 4-bit act -> a1 ----
  {
#pragma unroll
    for (int j = 0; j < 4; ++j) {
      const int ch = cg + 16 * j;
      const float g = wsf[F_BN0 + ch], be = wsf[F_BN0 + 64 + ch];
      const float m = wsf[F_BN0 + 128 + ch], rr = wsf[F_BN0 + 192 + ch];
#pragma unroll
      for (int r2 = 0; r2 < 2; ++r2)
        xa1[(rg * 2 + r2) * 64 + ch] = bn_act4(hs[r2][j], g, be, m, rr);
    }
  }

  // ---- layer 1: a1 -> a2 (lane = channel l, 8 rows) ----
  {
    const f4* wq1 = (const f4*)(wsf + F_WQ1);
    const f4* a14 = (const f4*)xa1;
    float a1c[8];
#pragma unroll
    for (int r = 0; r < 8; ++r) a1c[r] = 0.f;
#pragma unroll
    for (int cc = 0; cc < 16; ++cc) {
      const f4 wf = wq1[cc * 64 + l];
#pragma unroll
      for (int r = 0; r < 8; ++r) {
        const f4 xv = a14[r * 16 + cc];
        float a = a1c[r];
        a = __fmaf_rn(xv.x, wf.x, a);
        a = __fmaf_rn(xv.y, wf.y, a);
        a = __fmaf_rn(xv.z, wf.z, a);
        a = __fmaf_rn(xv.w, wf.w, a);
        a1c[r] = a;
      }
    }
    const float g = wsf[F_BN1 + l], be = wsf[F_BN1 + 64 + l];
    const float m = wsf[F_BN1 + 128 + l], rr = wsf[F_BN1 + 192 + l];
#pragma unroll
    for (int r = 0; r < 8; ++r)
      a2[r * 64 + l] = bn_act4(a1c[r], g, be, m, rr);
  }

  // ---- layer 2: a2 -> a1 ----
  {
    const f4* wq2 = (const f4*)(wsf + F_WQ2);
    const f4* a24 = (const f4*)a2;
    float a2c[8];
#pragma unroll
    for (int r = 0; r < 8; ++r) a2c[r] = 0.f;
#pragma unroll
    for (int cc = 0; cc < 16; ++cc) {
      const f4 wf = wq2[cc * 64 + l];
#pragma unroll
      for (int r = 0; r < 8; ++r) {
        const f4 xv = a24[r * 16 + cc];
        float a = a2c[r];
        a = __fmaf_rn(xv.x, wf.x, a);
        a = __fmaf_rn(xv.y, wf.y, a);
        a = __fmaf_rn(xv.z, wf.z, a);
        a = __fmaf_rn(xv.w, wf.w, a);
        a2c[r] = a;
      }
    }
    const float g = wsf[F_BN2 + l], be = wsf[F_BN2 + 64 + l];
    const float m = wsf[F_BN2 + 128 + l], rr = wsf[F_BN2 + 192 + l];
#pragma unroll
    for (int r = 0; r < 8; ++r)
      xa1[r * 64 + l] = bn_act4(a2c[r], g, be, m, rr);
  }

  // ---- layer 3: 10 outputs, BN affine, no act ----
  {
    const f4* wq3 = (const f4*)(wsf + F_WQ3);
    const f4* a14 = (const f4*)xa1;
    float a3c[8];
#pragma unroll
    for (int r = 0; r < 8; ++r) a3c[r] = 0.f;
#pragma unroll
    for (int cc = 0; cc < 16; ++cc) {
      const f4 wf = wq3[cc * 64 + l];
#pragma unroll
      for (int r = 0; r < 8; ++r) {
        const f4 xv = a14[r * 16 + cc];
        float a = a3c[r];
        a = __fmaf_rn(xv.x, wf.x, a);
        a = __fmaf_rn(xv.y, wf.y, a);
        a = __fmaf_rn(xv.z, wf.z, a);
        a = __fmaf_rn(xv.w, wf.w, a);
        a3c[r] = a;
      }
    }
    if (l < 10) {
      const float g = wsf[F_BN3 + l], be = wsf[F_BN3 + 16 + l];
      const float m = wsf[F_BN3 + 32 + l], rr = wsf[F_BN3 + 48 + l];
#pragma unroll
      for (int r = 0; r < 8; ++r) {
        const float o = __fadd_rn(__fmul_rn(__fmul_rn(g, __fsub_rn(a3c[r], m)), rr), be);
        out[(long)(row0w + r) * 10 + l] = o;
      }
    }
  }
}

extern "C" void kernel_launch(void* const* d_in, const int* in_sizes, int n_in,
                              void* d_out, int out_size, void* d_ws, size_t ws_size,
                              hipStream_t stream) {
  (void)in_sizes; (void)n_in; (void)out_size;
  InPtrs P;
  for (int i = 0; i < 25; ++i) P.p[i] = (const float*)d_in[i];
  float* wsf = (float*)d_ws;
  const int wf32 = (ws_size >= WS_NEED_F32) ? 1 : 0;
  qtfc_prep<<<193, 256, 0, stream>>>(P, wsf, wf32);
  if (wf32)
    qtfc_main<0><<<1024, 256, 0, stream>>>((const float*)d_in[0], wsf, (float*)d_out);
  else
    qtfc_main<1><<<1024, 256, 0, stream>>>((const float*)d_in[0], wsf, (float*)d_out);
}

// Round 13
// 292.551 us; speedup vs baseline: 2.9529x; 1.8187x over previous
//
#include <hip/hip_runtime.h>

typedef float4 f4;

// ---- ws float-offset layout ----
#define F_S0    0        // 64: per-channel W0 scale
#define F_BN0   64       // g[64] be[64] m[64] r[64]
#define F_BN1   320
#define F_BN2   576
#define F_BN3   832      // 256 floats (c<10 valid, rest 0)
#define F_WQ1   1088     // [16][64][4] fp32
#define F_WQ2   5184     // [16][64][4]
#define F_WQ3   9280     // [16][64][4] (zeros for c>=10)
#define F_WI0   13376    // int8 W0 tiled [768][64][4] = 196608 B
#define F_WQ0   62528    // fp32 W0 tiled [768][64][4] = 196608 floats
#define WS_NEED_F32 ((size_t)(F_WQ0 + 196608) * 4)

struct InPtrs { const float* p[25]; };

// ---------------- prep: fp32 scales/weights/BN consts (np-f32 exact ops) ----------------
__global__ __launch_bounds__(256) void qtfc_prep(InPtrs P, float* __restrict__ wsf, int wf32) {
#pragma clang fp contract(off)
  __shared__ float red[256];
  const int tid = threadIdx.x, b = blockIdx.x;
  if (b < 64) {
    const int c = b;                       // output channel
    const float* W = P.p[1];
    float mx = 0.f;
    for (int k = tid; k < 3072; k += 256) mx = fmaxf(mx, fabsf(W[c * 3072 + k]));
    red[tid] = mx; __syncthreads();
    for (int s = 128; s > 0; s >>= 1) { if (tid < s) red[tid] = fmaxf(red[tid], red[tid + s]); __syncthreads(); }
    const float sv = fmaxf(__fdiv_rn(red[0], 7.f), 1e-8f);
    signed char* wi = (signed char*)(wsf + F_WI0);
    for (int k = tid; k < 3072; k += 256) {
      const float r = rintf(__fdiv_rn(W[c * 3072 + k], sv));
      const int idx = (k >> 2) * 256 + c * 4 + (k & 3);   // [chunk][ch][4]
      wi[idx] = (signed char)(int)r;
      if (wf32) wsf[F_WQ0 + idx] = __fmul_rn(r, sv);
    }
    if (tid == 0) {
      wsf[F_S0 + c] = sv;
      const float gg = P.p[3][c], be = P.p[4][c], m = P.p[5][c], v = P.p[6][c];
      const float rr = __fdiv_rn(1.f, __fsqrt_rn(__fadd_rn(v, 1e-5f)));
      wsf[F_BN0 + c] = gg; wsf[F_BN0 + 64 + c] = be; wsf[F_BN0 + 128 + c] = m; wsf[F_BN0 + 192 + c] = rr;
    }
  } else if (b < 192) {
    const int lay = b >> 6, c = b & 63;    // lay = 1,2
    const float* W = P.p[1 + 6 * lay];
    red[tid] = (tid < 64) ? fabsf(W[c * 64 + tid]) : 0.f; __syncthreads();
    for (int s = 128; s > 0; s >>= 1) { if (tid < s) red[tid] = fmaxf(red[tid], red[tid + s]); __syncthreads(); }
    const float sv = fmaxf(__fdiv_rn(red[0], 7.f), 1e-8f);
    float* wq = wsf + (lay == 1 ? F_WQ1 : F_WQ2);
    if (tid < 64) {
      const int k = tid;
      wq[(k >> 2) * 256 + c * 4 + (k & 3)] = __fmul_rn(rintf(__fdiv_rn(W[c * 64 + k], sv)), sv);
    }
    if (tid == 0) {
      const int base = (lay == 1) ? F_BN1 : F_BN2;
      const float gg = P.p[3 + 6 * lay][c], be = P.p[4 + 6 * lay][c];
      const float m = P.p[5 + 6 * lay][c], v = P.p[6 + 6 * lay][c];
      const float rr = __fdiv_rn(1.f, __fsqrt_rn(__fadd_rn(v, 1e-5f)));
      wsf[base + c] = gg; wsf[base + 64 + c] = be; wsf[base + 128 + c] = m; wsf[base + 192 + c] = rr;
    }
  } else {
    // W3: zero-pad then per-tensor quant over 10x64
    for (int i = tid; i < 4096; i += 256) wsf[F_WQ3 + i] = 0.f;
    for (int i = tid; i < 256; i += 256) wsf[F_BN3 + i] = 0.f;
    __syncthreads();
    const float* W = P.p[19];
    float mx = 0.f;
    for (int k = tid; k < 640; k += 256) mx = fmaxf(mx, fabsf(W[k]));
    red[tid] = mx; __syncthreads();
    for (int s = 128; s > 0; s >>= 1) { if (tid < s) red[tid] = fmaxf(red[tid], red[tid + s]); __syncthreads(); }
    const float sv = fmaxf(__fdiv_rn(red[0], 7.f), 1e-8f);
    for (int i = tid; i < 640; i += 256) {
      const int c = i >> 6, k = i & 63;
      wsf[F_WQ3 + (k >> 2) * 256 + c * 4 + (k & 3)] = __fmul_rn(rintf(__fdiv_rn(W[i], sv)), sv);
    }
    if (tid < 10) {
      const float gg = P.p[21][tid], be = P.p[22][tid], m = P.p[23][tid], v = P.p[24][tid];
      const float rr = __fdiv_rn(1.f, __fsqrt_rn(__fadd_rn(v, 1e-5f)));
      wsf[F_BN3 + tid] = gg; wsf[F_BN3 + 16 + tid] = be; wsf[F_BN3 + 32 + tid] = m; wsf[F_BN3 + 48 + tid] = rr;
    }
  }
}

// ---------------- exact-np helpers ----------------
__device__ __forceinline__ float bn_act4(float hv, float g, float be, float m, float r) {
#pragma clang fp contract(off)
  const float bnv = __fadd_rn(__fmul_rn(__fmul_rn(g, __fsub_rn(hv, m)), r), be);
  const float y = fminf(fmaxf(bnv, -1.f), 1.f);
  return __fdiv_rn(rintf(__fmul_rn(y, 7.f)), 7.f);
}
__device__ __forceinline__ float lutq(float v, const float* lut) {
#pragma clang fp contract(off)
  const float y = fminf(fmaxf(v, -1.f), 1.f);
  const float r = rintf(__fmul_rn(y, 127.f));
  return lut[(int)r + 127];   // == __fdiv_rn(r, 127.f)
}
__device__ __forceinline__ f4 q4(f4 v, const float* lut) {
  f4 q; q.x = lutq(v.x, lut); q.y = lutq(v.y, lut); q.z = lutq(v.z, lut); q.w = lutq(v.w, lut);
  return q;
}
__device__ __forceinline__ f4 dec8(int d, float sv) {
#pragma clang fp contract(off)
  f4 w;
  w.x = __fmul_rn((float)((signed char)(d & 255)), sv);
  w.y = __fmul_rn((float)((signed char)((d >> 8) & 255)), sv);
  w.z = __fmul_rn((float)((signed char)((d >> 16) & 255)), sv);
  w.w = __fmul_rn((float)((signed char)((d >> 24) & 255)), sv);
  return w;
}

// ---- main: 8 rows/wave; lane = (rh=l>>5 -> rows rh*4..+3, c_lo=l&31 -> ch c_lo, c_lo+32) ----
// weights: block-shared LDS tile, staged via regs one tile ahead (2 barriers/tile)
template<int W8>
__global__ __launch_bounds__(256) void qtfc_main(const float* __restrict__ x,
                                                 const float* __restrict__ wsf,
                                                 float* __restrict__ out) {
#pragma clang fp contract(off)
  // [0:4096) wlds (1024 f4) | [4096:8448) x: 4 waves x (2 bufs x 8 rows x 17 f4) | [8448:8704) lut
  __shared__ __align__(16) float smem[8704];
  f4* wlds = (f4*)smem;
  const int tid = threadIdx.x, w = tid >> 6, l = tid & 63;
  float* xzone = smem + 4096 + w * 1088;
  float* lut = smem + 8448;
  const int row0w = blockIdx.x * 32 + w * 8;

  if (tid < 255) lut[tid] = __fdiv_rn((float)(tid - 127), 127.f);

  const int c_lo = l & 31, rh = l >> 5;
  const int sr = l >> 3, s0 = l & 7;
  const float* xb = x + (long)(row0w + sr) * 3072 + s0 * 4;
  f4* xsw = (f4*)xzone + sr * 17 + s0;            // stage: writes [0] and [8]
  const f4* xrd = (const f4*)xzone + rh * 68;     // read: [r*17 + cc] (+136 for buf1)
  const f4* wlb = wlds + c_lo;                    // weight read base (imm offsets)

  const f4* wgp = (const f4*)(wsf + F_WQ0) + tid; // fp32 src: +t*1024 + q*256
  const int* igp = (const int*)(wsf + F_WI0) + tid;
  float svt = 0.f;
  if (W8) svt = wsf[F_S0 + (tid & 63)];

  f4 wr0, wr1, wr2, wr3;
  int gw0 = 0, gw1 = 0, gw2 = 0, gw3 = 0;

  // issue tile-0 weight loads
  if (!W8) { wr0 = wgp[0]; wr1 = wgp[256]; wr2 = wgp[512]; wr3 = wgp[768]; }
  else     { gw0 = igp[0]; gw1 = igp[256]; gw2 = igp[512]; gw3 = igp[768]; }

  float acc[4][2], hs[4][2];
#pragma unroll
  for (int r = 0; r < 4; ++r) { acc[r][0] = 0.f; acc[r][1] = 0.f; hs[r][0] = 0.f; hs[r][1] = 0.f; }

  f4 gx0 = *(const f4*)(xb);
  f4 gx1 = *(const f4*)(xb + 32);
  __syncthreads();                                 // lut ready
  xsw[0] = q4(gx0, lut);
  xsw[8] = q4(gx1, lut);
  gx0 = *(const f4*)(xb + 64);
  gx1 = *(const f4*)(xb + 96);

#pragma unroll 1
  for (int t = 0; t < 48; ++t) {
    __syncthreads();                               // #1: all waves done reading tile t-1
    if (!W8) {
      wlds[tid] = wr0; wlds[tid + 256] = wr1; wlds[tid + 512] = wr2; wlds[tid + 768] = wr3;
    } else {
      wlds[tid] = dec8(gw0, svt);       wlds[tid + 256] = dec8(gw1, svt);
      wlds[tid + 512] = dec8(gw2, svt); wlds[tid + 768] = dec8(gw3, svt);
    }
    __syncthreads();                               // #2: tile t visible
    {
      const int tb = ((t + 1 < 48) ? t + 1 : 47) * 1024;
      if (!W8) { wr0 = wgp[tb]; wr1 = wgp[tb + 256]; wr2 = wgp[tb + 512]; wr3 = wgp[tb + 768]; }
      else     { gw0 = igp[tb]; gw1 = igp[tb + 256]; gw2 = igp[tb + 512]; gw3 = igp[tb + 768]; }
    }

    const f4* xw = xrd + (t & 1) * 136;
#pragma unroll 2
    for (int cc = 0; cc < 16; ++cc) {
      const f4 w0 = wlb[cc * 64];
      const f4 w1 = wlb[cc * 64 + 32];
#pragma unroll
      for (int r = 0; r < 4; ++r) {
        const f4 xv = xw[r * 17 + cc];
        float a0 = acc[r][0], a1 = acc[r][1];
        a0 = __fmaf_rn(xv.x, w0.x, a0); a1 = __fmaf_rn(xv.x, w1.x, a1);
        a0 = __fmaf_rn(xv.y, w0.y, a0); a1 = __fmaf_rn(xv.y, w1.y, a1);
        a0 = __fmaf_rn(xv.z, w0.z, a0); a1 = __fmaf_rn(xv.z, w1.z, a1);
        a0 = __fmaf_rn(xv.w, w0.w, a0); a1 = __fmaf_rn(xv.w, w1.w, a1);
        acc[r][0] = a0; acc[r][1] = a1;
      }
    }

    if (t < 47) {                                  // stage x tile t+1 (wave-private dbuf)
      f4* xsn = xsw + ((t + 1) & 1) * 136;
      xsn[0] = q4(gx0, lut);
      xsn[8] = q4(gx1, lut);
      const int tn = (t + 2 < 48) ? t + 2 : 47;
      gx0 = *(const f4*)(xb + tn * 64);
      gx1 = *(const f4*)(xb + tn * 64 + 32);
    }

    if ((t % 6) == 5) {                            // KC=384 boundary: block-sum combine
#pragma unroll
      for (int r = 0; r < 4; ++r) {
        hs[r][0] = __fadd_rn(hs[r][0], acc[r][0]); acc[r][0] = 0.f;
        hs[r][1] = __fadd_rn(hs[r][1], acc[r][1]); acc[r][1] = 0.f;
      }
    }
  }
  __syncthreads();                                 // weights region free for tail reuse

  float* xa1 = xzone;                              // a1 [8][64]
  float* a2 = smem + w * 512;                      // per-wave slice of wlds region

  // ---- layer-0 epilogue: BN + 4-bit act -> a1 ----
  {
    const float gL = wsf[F_BN0 + c_lo],       beL = wsf[F_BN0 + 64 + c_lo];
    const float mL = wsf[F_BN0 + 128 + c_lo], rL  = wsf[F_BN0 + 192 + c_lo];
    const float gH = wsf[F_BN0 + 32 + c_lo],  beH = wsf[F_BN0 + 96 + c_lo];
    const float mH = wsf[F_BN0 + 160 + c_lo], rH  = wsf[F_BN0 + 224 + c_lo];
#pragma unroll
    for (int r = 0; r < 4; ++r) {
      const int rr = rh * 4 + r;
      xa1[rr * 64 + c_lo]      = bn_act4(hs[r][0], gL, beL, mL, rL);
      xa1[rr * 64 + c_lo + 32] = bn_act4(hs[r][1], gH, beH, mH, rH);
    }
  }

  // ---- layer 1: a1 -> a2 (lane = channel l, 8 rows) ----
  {
    const f4* wq1 = (const f4*)(wsf + F_WQ1);
    const f4* a14 = (const f4*)xa1;
    float a1c[8];
#pragma unroll
    for (int r = 0; r < 8; ++r) a1c[r] = 0.f;
#pragma unroll
    for (int cc = 0; cc < 16; ++cc) {
      const f4 wf = wq1[cc * 64 + l];
#pragma unroll
      for (int r = 0; r < 8; ++r) {
        const f4 xv = a14[r * 16 + cc];
        float a = a1c[r];
        a = __fmaf_rn(xv.x, wf.x, a);
        a = __fmaf_rn(xv.y, wf.y, a);
        a = __fmaf_rn(xv.z, wf.z, a);
        a = __fmaf_rn(xv.w, wf.w, a);
        a1c[r] = a;
      }
    }
    const float g = wsf[F_BN1 + l], be = wsf[F_BN1 + 64 + l];
    const float m = wsf[F_BN1 + 128 + l], rr = wsf[F_BN1 + 192 + l];
#pragma unroll
    for (int r = 0; r < 8; ++r)
      a2[r * 64 + l] = bn_act4(a1c[r], g, be, m, rr);
  }

  // ---- layer 2: a2 -> a1 ----
  {
    const f4* wq2 = (const f4*)(wsf + F_WQ2);
    const f4* a24 = (const f4*)a2;
    float a2c[8];
#pragma unroll
    for (int r = 0; r < 8; ++r) a2c[r] = 0.f;
#pragma unroll
    for (int cc = 0; cc < 16; ++cc) {
      const f4 wf = wq2[cc * 64 + l];
#pragma unroll
      for (int r = 0; r < 8; ++r) {
        const f4 xv = a24[r * 16 + cc];
        float a = a2c[r];
        a = __fmaf_rn(xv.x, wf.x, a);
        a = __fmaf_rn(xv.y, wf.y, a);
        a = __fmaf_rn(xv.z, wf.z, a);
        a = __fmaf_rn(xv.w, wf.w, a);
        a2c[r] = a;
      }
    }
    const float g = wsf[F_BN2 + l], be = wsf[F_BN2 + 64 + l];
    const float m = wsf[F_BN2 + 128 + l], rr = wsf[F_BN2 + 192 + l];
#pragma unroll
    for (int r = 0; r < 8; ++r)
      xa1[r * 64 + l] = bn_act4(a2c[r], g, be, m, rr);
  }

  // ---- layer 3: 10 outputs, BN affine, no act ----
  {
    const f4* wq3 = (const f4*)(wsf + F_WQ3);
    const f4* a14 = (const f4*)xa1;
    float a3c[8];
#pragma unroll
    for (int r = 0; r < 8; ++r) a3c[r] = 0.f;
#pragma unroll
    for (int cc = 0; cc < 16; ++cc) {
      const f4 wf = wq3[cc * 64 + l];
#pragma unroll
      for (int r = 0; r < 8; ++r) {
        const f4 xv = a14[r * 16 + cc];
        float a = a3c[r];
        a = __fmaf_rn(xv.x, wf.x, a);
        a = __fmaf_rn(xv.y, wf.y, a);
        a = __fmaf_rn(xv.z, wf.z, a);
        a = __fmaf_rn(xv.w, wf.w, a);
        a3c[r] = a;
      }
    }
    if (l < 10) {
      const float g = wsf[F_BN3 + l], be = wsf[F_BN3 + 16 + l];
      const float m = wsf[F_BN3 + 32 + l], rr = wsf[F_BN3 + 48 + l];
#pragma unroll
      for (int r = 0; r < 8; ++r) {
        const float o = __fadd_rn(__fmul_rn(__fmul_rn(g, __fsub_rn(a3c[r], m)), rr), be);
        out[(long)(row0w + r) * 10 + l] = o;
      }
    }
  }
}

extern "C" void kernel_launch(void* const* d_in, const int* in_sizes, int n_in,
                              void* d_out, int out_size, void* d_ws, size_t ws_size,
                              hipStream_t stream) {
  (void)in_sizes; (void)n_in; (void)out_size;
  InPtrs P;
  for (int i = 0; i < 25; ++i) P.p[i] = (const float*)d_in[i];
  float* wsf = (float*)d_ws;
  const int wf32 = (ws_size >= WS_NEED_F32) ? 1 : 0;
  qtfc_prep<<<193, 256, 0, stream>>>(P, wsf, wf32);
  if (wf32)
    qtfc_main<0><<<1024, 256, 0, stream>>>((const float*)d_in[0], wsf, (float*)d_out);
  else
    qtfc_main<1><<<1024, 256, 0, stream>>>((const float*)d_in[0], wsf, (float*)d_out);
}